// Round 2
// baseline (3184.819 us; speedup 1.0000x reference)
//
#include <hip/hip_runtime.h>
#include <cstdint>
#include <cstddef>

static constexpr int TT = 1024;   // time steps
static constexpr int BB = 32;     // batch
static constexpr int CC = 256;    // channels (= 2H)
static constexpr int HH = 128;    // hidden per direction
static constexpr int GG = 512;    // 4H gates
static constexpr int MM = TT * BB;

__device__ __forceinline__ float fsig(float x) { return 1.f / (1.f + __expf(-x)); }
__device__ __forceinline__ float ftanh(float x) {
  float e = __expf(2.f * x);
  return 1.f - 2.f / (e + 1.f);
}

// ---------------- x[B][C][T] -> xs[T][B][C] ----------------
__global__ __launch_bounds__(256) void k_transpose_in(const float* __restrict__ x,
                                                      float* __restrict__ xs) {
  __shared__ float tile[32][33];
  const int t0 = blockIdx.x * 32, c0 = blockIdx.y * 32, b = blockIdx.z;
  const int tx = threadIdx.x, ty = threadIdx.y;
#pragma unroll
  for (int i = 0; i < 4; i++) {
    const int cc = ty + i * 8;
    tile[cc][tx] = x[((size_t)b * CC + (c0 + cc)) * TT + t0 + tx];
  }
  __syncthreads();
#pragma unroll
  for (int i = 0; i < 4; i++) {
    const int tt = ty + i * 8;
    xs[((size_t)(t0 + tt) * BB + b) * CC + c0 + tx] = tile[tx][tt];
  }
}

// ---------------- h2[T][B][C] -> out[B][C][T] ----------------
__global__ __launch_bounds__(256) void k_transpose_out(const float* __restrict__ h2,
                                                       float* __restrict__ out) {
  __shared__ float tile[32][33];
  const int t0 = blockIdx.x * 32, c0 = blockIdx.y * 32, b = blockIdx.z;
  const int tx = threadIdx.x, ty = threadIdx.y;
#pragma unroll
  for (int i = 0; i < 4; i++) {
    const int tt = ty + i * 8;
    tile[tt][tx] = h2[((size_t)(t0 + tt) * BB + b) * CC + c0 + tx];
  }
  __syncthreads();
#pragma unroll
  for (int i = 0; i < 4; i++) {
    const int cc = ty + i * 8;
    out[((size_t)b * CC + (c0 + cc)) * TT + t0 + tx] = tile[tx][cc];
  }
}

// ---------------- gx[d][m][g] = X[m][:]·W[d][g][:] + bih[d][g]+bhh[d][g] ----------------
// X: [M][256] row-major.  W: [D][512][256].  Tile: 128(M) x 64(N), K-step 16, 256 threads.
__global__ __launch_bounds__(256) void k_gemm_ih(const float* __restrict__ X,
                                                 const float* __restrict__ W,
                                                 const float* __restrict__ bih,
                                                 const float* __restrict__ bhh,
                                                 float* __restrict__ gx, int M) {
  const int d = blockIdx.z;
  const int row0 = blockIdx.y * 128;
  const int col0 = blockIdx.x * 64;
  const float* Wd = W + (size_t)d * GG * CC;
  __shared__ float As[16][132];  // [k][m], padded: 132%32=4 -> 2-way max (free); 528B row, 16B aligned
  __shared__ float Ws[16][68];   // [k][n]
  const int tid = threadIdx.x;
  const int tm = tid >> 4;        // 0..15 -> 8 rows each
  const int tn = tid & 15;        // 0..15 -> 4 cols each
  const int lr = tid >> 2;        // 0..63
  const int lk = (tid & 3) * 4;   // 0,4,8,12

  float acc[8][4] = {};
  for (int k0 = 0; k0 < CC; k0 += 16) {
    const float4 a0 = *(const float4*)&X[(size_t)(row0 + lr) * CC + k0 + lk];
    const float4 a1 = *(const float4*)&X[(size_t)(row0 + 64 + lr) * CC + k0 + lk];
    const float4 wv = *(const float4*)&Wd[(size_t)(col0 + lr) * CC + k0 + lk];
    __syncthreads();  // protect LDS from previous iteration's readers
    As[lk + 0][lr] = a0.x; As[lk + 1][lr] = a0.y; As[lk + 2][lr] = a0.z; As[lk + 3][lr] = a0.w;
    As[lk + 0][64 + lr] = a1.x; As[lk + 1][64 + lr] = a1.y; As[lk + 2][64 + lr] = a1.z; As[lk + 3][64 + lr] = a1.w;
    Ws[lk + 0][lr] = wv.x; Ws[lk + 1][lr] = wv.y; Ws[lk + 2][lr] = wv.z; Ws[lk + 3][lr] = wv.w;
    __syncthreads();
#pragma unroll
    for (int kk = 0; kk < 16; kk++) {
      const float4 av0 = *(const float4*)&As[kk][tm * 8];
      const float4 av1 = *(const float4*)&As[kk][tm * 8 + 4];
      const float4 bv = *(const float4*)&Ws[kk][tn * 4];
      const float a[8] = {av0.x, av0.y, av0.z, av0.w, av1.x, av1.y, av1.z, av1.w};
      const float bb4[4] = {bv.x, bv.y, bv.z, bv.w};
#pragma unroll
      for (int i = 0; i < 8; i++)
#pragma unroll
        for (int j = 0; j < 4; j++) acc[i][j] = fmaf(a[i], bb4[j], acc[i][j]);
    }
  }
  float bias[4];
#pragma unroll
  for (int j = 0; j < 4; j++) {
    const int col = col0 + tn * 4 + j;
    bias[j] = bih[d * GG + col] + bhh[d * GG + col];
  }
#pragma unroll
  for (int i = 0; i < 8; i++) {
    const int row = row0 + tm * 8 + i;
    float4 o;
    o.x = acc[i][0] + bias[0];
    o.y = acc[i][1] + bias[1];
    o.z = acc[i][2] + bias[2];
    o.w = acc[i][3] + bias[3];
    *(float4*)&gx[((size_t)d * M + row) * GG + col0 + tn * 4] = o;
  }
}

// ---------------- persistent recurrence: one WG per (d,b); W_hh rows in VGPRs ----------------
// gx: [D][T][B][512]; Whh: [D][512][128] (layer base); hout: [T][B][256]
__global__ __launch_bounds__(512, 2) void k_lstm_rec(const float* __restrict__ gx,
                                                     const float* __restrict__ Whh,
                                                     float* __restrict__ hout) {
  const int b = blockIdx.x & 31;
  const int d = blockIdx.x >> 5;
  const int tid = threadIdx.x;  // = gate row g (0..511)
  __shared__ __align__(16) float h_s[HH];
  __shared__ float a_s[GG];

  float4 w4[32];  // W_hh[d][tid][0:128] resident in VGPRs
  {
    const float4* wrow = (const float4*)(Whh + ((size_t)d * GG + tid) * HH);
#pragma unroll
    for (int k = 0; k < 32; k++) w4[k] = wrow[k];
  }
  if (tid < HH) h_s[tid] = 0.f;
  float c = 0.f;

  const float* gxb = gx + ((size_t)d * TT * BB + b) * (size_t)GG;
  const size_t step_stride = (size_t)BB * GG;
  int t = d ? (TT - 1) : 0;
  const int tdir = d ? -1 : 1;
  float gxc = gxb[(size_t)t * step_stride + tid];
  __syncthreads();

  for (int s = 0; s < TT; s++) {
    // prefetch next step's gx (independent of h) -> hides HBM latency under dot loop
    float gxn = 0.f;
    if (s + 1 < TT) gxn = gxb[(size_t)(t + tdir) * step_stride + tid];

    float acc0 = gxc, acc1 = 0.f, acc2 = 0.f, acc3 = 0.f;
#pragma unroll
    for (int k = 0; k < 32; k++) {
      const float4 hv = *(const float4*)&h_s[k * 4];  // broadcast read
      acc0 = fmaf(w4[k].x, hv.x, acc0);
      acc1 = fmaf(w4[k].y, hv.y, acc1);
      acc2 = fmaf(w4[k].z, hv.z, acc2);
      acc3 = fmaf(w4[k].w, hv.w, acc3);
    }
    a_s[tid] = (acc0 + acc1) + (acc2 + acc3);
    __syncthreads();

    if (tid < HH) {
      const float i_g = fsig(a_s[tid]);
      const float f_g = fsig(a_s[HH + tid]);
      const float g_g = ftanh(a_s[2 * HH + tid]);
      const float o_g = fsig(a_s[3 * HH + tid]);
      c = f_g * c + i_g * g_g;
      const float h = o_g * ftanh(c);
      h_s[tid] = h;
      hout[((size_t)t * BB + b) * CC + d * HH + tid] = h;
    }
    __syncthreads();
    gxc = gxn;
    t += tdir;
  }
}

extern "C" void kernel_launch(void* const* d_in, const int* in_sizes, int n_in,
                              void* d_out, int out_size, void* d_ws, size_t ws_size,
                              hipStream_t stream) {
  const float* x    = (const float*)d_in[0];
  const float* W_ih = (const float*)d_in[1];  // [2][2][512][256]
  const float* W_hh = (const float*)d_in[2];  // [2][2][512][128]
  const float* b_ih = (const float*)d_in[3];  // [2][2][512]
  const float* b_hh = (const float*)d_in[4];
  float* out = (float*)d_out;

  if (ws_size < (size_t)160 * 1024 * 1024) return;  // need xs(32MiB)+gx(128MiB)

  char* ws = (char*)d_ws;
  float* xs = (float*)ws;                                   // [T][B][C] 32 MiB
  float* gxbuf = (float*)(ws + (size_t)32 * 1024 * 1024);   // [D][M][512] 128 MiB
  float* h1 = out;  // layer-0 hidden staged in d_out (dead before final transpose)
  float* h2 = xs;   // layer-1 hidden reuses xs region (xs dead after layer-0 GEMM)

  const dim3 tb(32, 8);
  const dim3 tg(TT / 32, CC / 32, BB);

  k_transpose_in<<<tg, tb, 0, stream>>>(x, xs);
  k_gemm_ih<<<dim3(GG / 64, MM / 128, 2), 256, 0, stream>>>(xs, W_ih, b_ih, b_hh, gxbuf, MM);
  k_lstm_rec<<<64, 512, 0, stream>>>(gxbuf, W_hh, h1);
  k_gemm_ih<<<dim3(GG / 64, MM / 128, 2), 256, 0, stream>>>(h1, W_ih + 2 * GG * CC,
                                                            b_ih + 2 * GG, b_hh + 2 * GG, gxbuf, MM);
  k_lstm_rec<<<64, 512, 0, stream>>>(gxbuf, W_hh + 2 * GG * HH, h2);
  k_transpose_out<<<tg, tb, 0, stream>>>(h2, out);
}

// Round 3
// 3127.163 us; speedup vs baseline: 1.0184x; 1.0184x over previous
//
#include <hip/hip_runtime.h>
#include <cstdint>
#include <cstddef>

static constexpr int TT = 1024;   // time steps
static constexpr int BB = 32;     // batch
static constexpr int CC = 256;    // channels (= 2H)
static constexpr int HH = 128;    // hidden per direction
static constexpr int GG = 512;    // 4H gates
static constexpr int MM = TT * BB;

__device__ __forceinline__ float fsig(float x) { return 1.f / (1.f + __expf(-x)); }
__device__ __forceinline__ float ftanh(float x) {
  float e = __expf(2.f * x);
  return 1.f - 2.f / (e + 1.f);
}

// ---------------- x[B][C][T] -> xs[T][B][C] ----------------
__global__ __launch_bounds__(256) void k_transpose_in(const float* __restrict__ x,
                                                      float* __restrict__ xs) {
  __shared__ float tile[32][33];
  const int t0 = blockIdx.x * 32, c0 = blockIdx.y * 32, b = blockIdx.z;
  const int tx = threadIdx.x, ty = threadIdx.y;
#pragma unroll
  for (int i = 0; i < 4; i++) {
    const int cc = ty + i * 8;
    tile[cc][tx] = x[((size_t)b * CC + (c0 + cc)) * TT + t0 + tx];
  }
  __syncthreads();
#pragma unroll
  for (int i = 0; i < 4; i++) {
    const int tt = ty + i * 8;
    xs[((size_t)(t0 + tt) * BB + b) * CC + c0 + tx] = tile[tx][tt];
  }
}

// ---------------- h2[T][B][C] -> out[B][C][T] ----------------
__global__ __launch_bounds__(256) void k_transpose_out(const float* __restrict__ h2,
                                                       float* __restrict__ out) {
  __shared__ float tile[32][33];
  const int t0 = blockIdx.x * 32, c0 = blockIdx.y * 32, b = blockIdx.z;
  const int tx = threadIdx.x, ty = threadIdx.y;
#pragma unroll
  for (int i = 0; i < 4; i++) {
    const int tt = ty + i * 8;
    tile[tt][tx] = h2[((size_t)(t0 + tt) * BB + b) * CC + c0 + tx];
  }
  __syncthreads();
#pragma unroll
  for (int i = 0; i < 4; i++) {
    const int cc = ty + i * 8;
    out[((size_t)b * CC + (c0 + cc)) * TT + t0 + tx] = tile[tx][cc];
  }
}

// ---------------- gx[d][m][g] = X[m][:]·W[d][g][:] + bih[d][g]+bhh[d][g] ----------------
// X: [M][256] row-major.  W: [D][512][256].  Tile: 128(M) x 64(N), K-step 16, 256 threads.
__global__ __launch_bounds__(256) void k_gemm_ih(const float* __restrict__ X,
                                                 const float* __restrict__ W,
                                                 const float* __restrict__ bih,
                                                 const float* __restrict__ bhh,
                                                 float* __restrict__ gx, int M) {
  const int d = blockIdx.z;
  const int row0 = blockIdx.y * 128;
  const int col0 = blockIdx.x * 64;
  const float* Wd = W + (size_t)d * GG * CC;
  __shared__ float As[16][132];  // [k][m], padded
  __shared__ float Ws[16][68];   // [k][n]
  const int tid = threadIdx.x;
  const int tm = tid >> 4;        // 0..15 -> 8 rows each
  const int tn = tid & 15;        // 0..15 -> 4 cols each
  const int lr = tid >> 2;        // 0..63
  const int lk = (tid & 3) * 4;   // 0,4,8,12

  float acc[8][4] = {};
  for (int k0 = 0; k0 < CC; k0 += 16) {
    const float4 a0 = *(const float4*)&X[(size_t)(row0 + lr) * CC + k0 + lk];
    const float4 a1 = *(const float4*)&X[(size_t)(row0 + 64 + lr) * CC + k0 + lk];
    const float4 wv = *(const float4*)&Wd[(size_t)(col0 + lr) * CC + k0 + lk];
    __syncthreads();  // protect LDS from previous iteration's readers
    As[lk + 0][lr] = a0.x; As[lk + 1][lr] = a0.y; As[lk + 2][lr] = a0.z; As[lk + 3][lr] = a0.w;
    As[lk + 0][64 + lr] = a1.x; As[lk + 1][64 + lr] = a1.y; As[lk + 2][64 + lr] = a1.z; As[lk + 3][64 + lr] = a1.w;
    Ws[lk + 0][lr] = wv.x; Ws[lk + 1][lr] = wv.y; Ws[lk + 2][lr] = wv.z; Ws[lk + 3][lr] = wv.w;
    __syncthreads();
#pragma unroll
    for (int kk = 0; kk < 16; kk++) {
      const float4 av0 = *(const float4*)&As[kk][tm * 8];
      const float4 av1 = *(const float4*)&As[kk][tm * 8 + 4];
      const float4 bv = *(const float4*)&Ws[kk][tn * 4];
      const float a[8] = {av0.x, av0.y, av0.z, av0.w, av1.x, av1.y, av1.z, av1.w};
      const float bb4[4] = {bv.x, bv.y, bv.z, bv.w};
#pragma unroll
      for (int i = 0; i < 8; i++)
#pragma unroll
        for (int j = 0; j < 4; j++) acc[i][j] = fmaf(a[i], bb4[j], acc[i][j]);
    }
  }
  float bias[4];
#pragma unroll
  for (int j = 0; j < 4; j++) {
    const int col = col0 + tn * 4 + j;
    bias[j] = bih[d * GG + col] + bhh[d * GG + col];
  }
#pragma unroll
  for (int i = 0; i < 8; i++) {
    const int row = row0 + tm * 8 + i;
    float4 o;
    o.x = acc[i][0] + bias[0];
    o.y = acc[i][1] + bias[1];
    o.z = acc[i][2] + bias[2];
    o.w = acc[i][3] + bias[3];
    *(float4*)&gx[((size_t)d * M + row) * GG + col0 + tn * 4] = o;
  }
}

// ---------------- persistent recurrence: one WG per (d,b) ----------------
// 1024 threads: 2 threads per gate row, each holds 64 weights (16 float4 = 64 VGPRs)
// so W_hh stays register-resident (R1's 512-thr/128-float version spilled: VGPR=88<128).
// gx: [D][T][B][512]; Whh: [D][512][128] (layer base); hout: [T][B][256]
__global__ __launch_bounds__(1024, 4) void k_lstm_rec(const float* __restrict__ gx,
                                                      const float* __restrict__ Whh,
                                                      float* __restrict__ hout) {
  const int b = blockIdx.x & 31;
  const int d = blockIdx.x >> 5;
  const int tid = threadIdx.x;
  const int g = tid >> 1;       // gate row 0..511
  const int half = tid & 1;     // which 64-wide K-chunk
  __shared__ __align__(16) float h_s[HH];
  __shared__ float a_s[GG];

  float4 w4[16];  // 64 weights resident in VGPRs
  {
    const float4* wrow = (const float4*)(Whh + ((size_t)d * GG + g) * HH + half * 64);
#pragma unroll
    for (int k = 0; k < 16; k++) w4[k] = wrow[k];
  }
  if (tid < HH) h_s[tid] = 0.f;
  float c = 0.f;

  const float* gxb = gx + ((size_t)d * TT * BB + b) * (size_t)GG;
  const size_t step_stride = (size_t)BB * GG;
  int t = d ? (TT - 1) : 0;
  const int tdir = d ? -1 : 1;
  float gxc = gxb[(size_t)t * step_stride + g];
  __syncthreads();

  for (int s = 0; s < TT; s++) {
    // prefetch next step's gx (independent of h) -> hides latency under dot loop
    float gxn = 0.f;
    if (s + 1 < TT) gxn = gxb[(size_t)(t + tdir) * step_stride + g];

    const float* hbase = h_s + half * 64;
    float acc0 = 0.f, acc1 = 0.f, acc2 = 0.f, acc3 = 0.f;
#pragma unroll
    for (int k = 0; k < 16; k++) {
      const float4 hv = *(const float4*)&hbase[k * 4];  // 2-address wave broadcast (free)
      acc0 = fmaf(w4[k].x, hv.x, acc0);
      acc1 = fmaf(w4[k].y, hv.y, acc1);
      acc2 = fmaf(w4[k].z, hv.z, acc2);
      acc3 = fmaf(w4[k].w, hv.w, acc3);
    }
    float v = (acc0 + acc1) + (acc2 + acc3);
    v += __shfl_xor(v, 1, 64);          // combine the two K-halves (adjacent lanes)
    if (!half) a_s[g] = v + gxc;
    __syncthreads();

    if (tid < HH) {
      const float i_g = fsig(a_s[tid]);
      const float f_g = fsig(a_s[HH + tid]);
      const float g_g = ftanh(a_s[2 * HH + tid]);
      const float o_g = fsig(a_s[3 * HH + tid]);
      c = f_g * c + i_g * g_g;
      const float h = o_g * ftanh(c);
      h_s[tid] = h;
      hout[((size_t)t * BB + b) * CC + d * HH + tid] = h;
    }
    __syncthreads();
    gxc = gxn;
    t += tdir;
  }
}

extern "C" void kernel_launch(void* const* d_in, const int* in_sizes, int n_in,
                              void* d_out, int out_size, void* d_ws, size_t ws_size,
                              hipStream_t stream) {
  const float* x    = (const float*)d_in[0];
  const float* W_ih = (const float*)d_in[1];  // [2][2][512][256]
  const float* W_hh = (const float*)d_in[2];  // [2][2][512][128]
  const float* b_ih = (const float*)d_in[3];  // [2][2][512]
  const float* b_hh = (const float*)d_in[4];
  float* out = (float*)d_out;

  if (ws_size < (size_t)160 * 1024 * 1024) return;  // need xs(32MiB)+gx(128MiB)

  char* ws = (char*)d_ws;
  float* xs = (float*)ws;                                   // [T][B][C] 32 MiB
  float* gxbuf = (float*)(ws + (size_t)32 * 1024 * 1024);   // [D][M][512] 128 MiB
  float* h1 = out;  // layer-0 hidden staged in d_out (dead before final transpose)
  float* h2 = xs;   // layer-1 hidden reuses xs region (xs dead after layer-0 GEMM)

  const dim3 tb(32, 8);
  const dim3 tg(TT / 32, CC / 32, BB);

  k_transpose_in<<<tg, tb, 0, stream>>>(x, xs);
  k_gemm_ih<<<dim3(GG / 64, MM / 128, 2), 256, 0, stream>>>(xs, W_ih, b_ih, b_hh, gxbuf, MM);
  k_lstm_rec<<<64, 1024, 0, stream>>>(gxbuf, W_hh, h1);
  k_gemm_ih<<<dim3(GG / 64, MM / 128, 2), 256, 0, stream>>>(h1, W_ih + 2 * GG * CC,
                                                            b_ih + 2 * GG, b_hh + 2 * GG, gxbuf, MM);
  k_lstm_rec<<<64, 1024, 0, stream>>>(gxbuf, W_hh + 2 * GG * HH, h2);
  k_transpose_out<<<tg, tb, 0, stream>>>(h2, out);
}